// Round 17
// baseline (542.774 us; speedup 1.0000x reference)
//
#include <hip/hip_runtime.h>
#include <cstdint>
#include <cstddef>

// Problem constants (fixed by the reference)
#define NN 50000
#define EE 400000
#define FIN 128
#define HH 3
#define DD 64
#define GG 64
#define PP 64
#define HD 192   // H*D

typedef short bf16x8 __attribute__((ext_vector_type(8)));   // 8 bf16 (4 VGPRs)
typedef float f32x4 __attribute__((ext_vector_type(4)));

__device__ inline float wsum(float v) {
#pragma unroll
    for (int m = 32; m > 0; m >>= 1) v += __shfl_xor(v, m, 64);
    return v;
}
__device__ inline int wsumi(int v) {
#pragma unroll
    for (int m = 32; m > 0; m >>= 1) v += __shfl_xor(v, m, 64);
    return v;
}

// bf16 <-> f32 (RNE)
__device__ inline float bf2f(unsigned short u) {
    union { unsigned int i; float f; } x; x.i = ((unsigned int)u) << 16; return x.f;
}
__device__ inline unsigned short f2bf(float f) {
    union { float f; unsigned int i; } x; x.f = f;
    unsigned int r = x.i + 0x7FFFu + ((x.i >> 16) & 1u);
    return (unsigned short)(r >> 16);
}

// ---------------- CSR build (dst-sorted edge order) ----------------
__global__ void k_count(const int* __restrict__ dst, int* __restrict__ counts) {
    int e = blockIdx.x * 256 + threadIdx.x;
    if (e < EE) atomicAdd(&counts[dst[e]], 1);
}

__global__ void k_scan_block(const int* __restrict__ in, int* __restrict__ out,
                             int* __restrict__ bsums) {
    __shared__ int tmp[1024];
    int tid = threadIdx.x;
    int i = blockIdx.x * 1024 + tid;
    int v = (i < NN) ? in[i] : 0;
    tmp[tid] = v;
    __syncthreads();
    for (int off = 1; off < 1024; off <<= 1) {
        int t = (tid >= off) ? tmp[tid - off] : 0;
        __syncthreads();
        tmp[tid] += t;
        __syncthreads();
    }
    if (i < NN) out[i] = tmp[tid] - v;
    if (tid == 1023) bsums[blockIdx.x] = tmp[1023];
}

// fused: each block computes its own bsums-prefix (nb <= 64) then adds it
__global__ void k_scan_add(int* __restrict__ row_ptr, const int* __restrict__ bsums, int nb) {
    __shared__ int sbase;
    int tid = threadIdx.x;
    if (tid < 64) {
        int v = (tid < blockIdx.x) ? bsums[tid] : 0;   // blockIdx.x <= nb <= 64
        v = wsumi(v);
        if (tid == 0) sbase = v;
    }
    __syncthreads();
    int i = blockIdx.x * 1024 + tid;
    if (i < NN) row_ptr[i] += sbase;
}

__global__ void k_scatter(const int* __restrict__ src, const int* __restrict__ dst,
                          const int* __restrict__ row_ptr, int* __restrict__ cursor,
                          int* __restrict__ csr_src, int* __restrict__ csr_dst) {
    int e = blockIdx.x * 256 + threadIdx.x;
    if (e >= EE) return;
    int v = dst[e];
    int pos = row_ptr[v] + atomicAdd(&cursor[v], 1);
    csr_src[pos] = src[e];
    csr_dst[pos] = v;
}

// ---------------- weight pre-pack: ALL 6 matrices, one dispatch ----------------
__device__ inline void pack_one(const float* __restrict__ W, unsigned short* __restrict__ WP,
                                int id, int Kc) {
    int lane = id & 63;
    int kc = (id >> 6) % Kc;
    int ct = (id >> 6) / Kc;
    int n = ct * 16 + (lane & 15);
    int kb = kc * 32 + (lane >> 4) * 8;
#pragma unroll
    for (int j = 0; j < 8; j++)
        WP[(unsigned)id * 8 + j] = f2bf(W[(unsigned)(kb + j) * HD + n]);
}

#define IDS128 (12 * 4 * 64)   // 3072
#define IDS192 (12 * 6 * 64)   // 4608
__global__ void k_pack_all(const float* W1s, const float* W1d,
                           const float* W2s, const float* W2d,
                           const float* W3s, const float* W3d,
                           unsigned short* P1s, unsigned short* P1d,
                           unsigned short* P2s, unsigned short* P2d,
                           unsigned short* P3s, unsigned short* P3d) {
    int idx = blockIdx.x * 256 + threadIdx.x;
    if (idx < IDS128) { pack_one(W1s, P1s, idx, 4); return; }
    idx -= IDS128;
    if (idx < IDS128) { pack_one(W1d, P1d, idx, 4); return; }
    idx -= IDS128;
    if (idx < IDS192) { pack_one(W2s, P2s, idx, 6); return; }
    idx -= IDS192;
    if (idx < IDS192) { pack_one(W2d, P2d, idx, 6); return; }
    idx -= IDS192;
    if (idx < IDS192) { pack_one(W3s, P3s, idx, 6); return; }
    idx -= IDS192;
    if (idx < IDS192) { pack_one(W3d, P3d, idx, 6); return; }
}

// ---------------- MFMA GEMM: [N,K]@[K,192] x2 (Ws,Wd); outputs bf16 ------------
// (R16 version: M-tile = 16, LDS epilogue, unsigned 32-bit indexing)
template <int K, bool FUSE>
__global__ __launch_bounds__(256) void k_gemm_mfma(const float* __restrict__ X,
                                                   const float* __restrict__ DENp,
                                                   const float* __restrict__ bprev,
                                                   const unsigned short* __restrict__ WPs,
                                                   const unsigned short* __restrict__ WPd,
                                                   unsigned short* __restrict__ FS,
                                                   unsigned short* __restrict__ FD) {
    constexpr int Kc = K / 32;
    __shared__ unsigned short xs[16][K + 8];
    __shared__ unsigned short cs[16][392];   // [row][0..191]=FS cols, [192..383]=FD cols
    int tid = threadIdx.x;
    int row0 = blockIdx.x * 16;
    for (int idx = tid; idx < 16 * K; idx += 256) {
        int r = idx / K, k = idx - r * K;
        int row = row0 + r;
        float val;
        if (FUSE) {
            float den = DENp[(unsigned)(row * 4 + (k >> 6))];
            val = X[(unsigned)(row * K + k)] / fmaxf(den, 1e-9f) + bprev[k];
        } else {
            val = X[(unsigned)(row * K + k)];
        }
        xs[r][k] = f2bf(val);
    }
    __syncthreads();

    int lane = tid & 63, wv = tid >> 6;
    int m = lane & 15, quad = lane >> 4;
    f32x4 acc[6];
#pragma unroll
    for (int t = 0; t < 6; t++) acc[t] = (f32x4){0.f, 0.f, 0.f, 0.f};

    for (int kc = 0; kc < Kc; kc++) {
        bf16x8 a = *(const bf16x8*)&xs[m][kc * 32 + quad * 8];
#pragma unroll
        for (int t = 0; t < 6; t++) {
            int ct = wv * 6 + t;                       // 0..23
            const unsigned short* wp = (ct < 12) ? WPs : WPd;
            int c = (ct < 12) ? ct : ct - 12;
            bf16x8 b = *(const bf16x8*)&wp[(unsigned)(((c * Kc + kc) * 64 + lane) * 8)];
            acc[t] = __builtin_amdgcn_mfma_f32_16x16x32_bf16(a, b, acc[t], 0, 0, 0);
        }
    }
#pragma unroll
    for (int t = 0; t < 6; t++) {
        int ct = wv * 6 + t;
#pragma unroll
        for (int r = 0; r < 4; r++)
            cs[quad * 4 + r][ct * 16 + m] = f2bf(acc[t][r]);
    }
    __syncthreads();
#pragma unroll
    for (int it = 0; it < 3; it++) {
        int c = tid + it * 256;
        int hm = c / 384;                              // 0=FS, 1=FD
        int cc = c - hm * 384;
        int row = cc / 24, ch = cc - row * 24;
        unsigned short* OUT = hm ? FD : FS;
        *(bf16x8*)&OUT[(unsigned)((row0 + row) * HD + ch * 8)] =
            *(const bf16x8*)&cs[row][hm * 192 + ch * 8];
    }
}

// ---------------- edge-parallel GATv2 on dst-sorted edges + run merge ----------
// (R15/R10 version VERBATIM: 64-lane wave per 8 edges, size_t element indexing,
// separate csr arrays — measured 86.7 us twice with FETCH 75.9 / WRITE 73.2 MB)
#define ECH 8
__global__ __launch_bounds__(256) void k_edge_atomic(const int* __restrict__ csr_src,
                                                     const int* __restrict__ csr_dst,
                                                     const unsigned short* __restrict__ FS,
                                                     const unsigned short* __restrict__ FD,
                                                     const float* __restrict__ A,
                                                     float* __restrict__ ACC,
                                                     float* __restrict__ DEN) {
    int wv = threadIdx.x >> 6, lane = threadIdx.x & 63;
    int e0 = blockIdx.x * (4 * ECH) + wv * ECH;
    float a0 = A[lane], a1 = A[64 + lane], a2 = A[128 + lane];

    int u[ECH], v[ECH];
#pragma unroll
    for (int i = 0; i < ECH; i++) {
        u[i] = csr_src[e0 + i];
        v[i] = csr_dst[e0 + i];
    }
    float f[ECH][3], g[ECH][3];
#pragma unroll
    for (int i = 0; i < ECH; i++) {
        size_t bu = (size_t)u[i] * HD, bv = (size_t)v[i] * HD;
        f[i][0] = bf2f(FS[bu + lane]);
        f[i][1] = bf2f(FS[bu + 64 + lane]);
        f[i][2] = bf2f(FS[bu + 128 + lane]);
        g[i][0] = bf2f(FD[bv + lane]);
        g[i][1] = bf2f(FD[bv + 64 + lane]);
        g[i][2] = bf2f(FD[bv + 128 + lane]);
    }
    float w[ECH][3];
#pragma unroll
    for (int i = 0; i < ECH; i++) {
        float s0 = f[i][0] + g[i][0]; s0 = s0 > 0.f ? s0 : 0.2f * s0;
        float s1 = f[i][1] + g[i][1]; s1 = s1 > 0.f ? s1 : 0.2f * s1;
        float s2 = f[i][2] + g[i][2]; s2 = s2 > 0.f ? s2 : 0.2f * s2;
        w[i][0] = s0 * a0; w[i][1] = s1 * a1; w[i][2] = s2 * a2;
    }
#pragma unroll
    for (int i = 0; i < ECH; i++)
#pragma unroll
        for (int h = 0; h < 3; h++) w[i][h] = wsum(w[i][h]);
#pragma unroll
    for (int i = 0; i < ECH; i++)
#pragma unroll
        for (int h = 0; h < 3; h++) w[i][h] = __expf(w[i][h]);

    // run-merge: consecutive sorted edges sharing dst -> single atomic flush
    float r0 = 0.f, r1 = 0.f, r2 = 0.f, d0 = 0.f, d1 = 0.f, d2 = 0.f;
    int vcur = v[0];
#pragma unroll
    for (int i = 0; i < ECH; i++) {
        if (v[i] != vcur) {
            size_t bv = (size_t)vcur * HD;
            atomicAdd(&ACC[bv + lane], r0);
            atomicAdd(&ACC[bv + 64 + lane], r1);
            atomicAdd(&ACC[bv + 128 + lane], r2);
            if (lane < 3) {
                float dv = lane == 0 ? d0 : (lane == 1 ? d1 : d2);
                atomicAdd(&DEN[vcur * 4 + lane], dv);
            }
            vcur = v[i];
            r0 = r1 = r2 = 0.f; d0 = d1 = d2 = 0.f;
        }
        r0 += w[i][0] * f[i][0]; d0 += w[i][0];
        r1 += w[i][1] * f[i][1]; d1 += w[i][1];
        r2 += w[i][2] * f[i][2]; d2 += w[i][2];
    }
    {
        size_t bv = (size_t)vcur * HD;
        atomicAdd(&ACC[bv + lane], r0);
        atomicAdd(&ACC[bv + 64 + lane], r1);
        atomicAdd(&ACC[bv + 128 + lane], r2);
        if (lane < 3) {
            float dv = lane == 0 ? d0 : (lane == 1 ? d1 : d2);
            atomicAdd(&DEN[vcur * 4 + lane], dv);
        }
    }
}

// ---------------- final: per-graph mean (256 blocks = 4 per graph) -------------
__global__ __launch_bounds__(256) void k_graph_mean(const float* __restrict__ ACC,
                                                    const float* __restrict__ DEN,
                                                    const float* __restrict__ bias,
                                                    const int* __restrict__ gids,
                                                    float* __restrict__ gsum,
                                                    int* __restrict__ gcnt) {
    int g = blockIdx.x >> 2, q = blockIdx.x & 3;
    int lo, hi;
    {
        int a = 0, b = NN;
        while (a < b) { int m = (a + b) >> 1; if (gids[m] < g) a = m + 1; else b = m; }
        lo = a;
        b = NN;
        while (a < b) { int m = (a + b) >> 1; if (gids[m] < g + 1) a = m + 1; else b = m; }
        hi = a;
    }
    int len = hi - lo;
    int qlen = (len + 3) >> 2;
    int s = lo + q * qlen;
    int e = s + qlen; if (e > hi) e = hi;
    int lane = threadIdx.x & 63, wv = threadIdx.x >> 6;

    float acc = 0.f;
    for (int v = s + wv; v < e; v += 4) {
        float r = 0.f;
#pragma unroll
        for (int h = 0; h < 3; h++) {
            float den = DEN[(unsigned)(v * 4 + h)];
            r += ACC[(unsigned)(v * HD + h * 64 + lane)] / fmaxf(den, 1e-9f) + bias[h * 64 + lane];
        }
        acc += r * (1.f / 3.f);
    }
    __shared__ float red[4][64];
    red[wv][lane] = acc;
    __syncthreads();
    if (wv == 0) {
        float t = red[0][lane] + red[1][lane] + red[2][lane] + red[3][lane];
        if (e > s) {
            atomicAdd(&gsum[g * 64 + lane], t);
            if (lane == 0) atomicAdd(&gcnt[g], e - s);
        }
    }
}

// ---------------- head: one block PER GRAPH (64 blocks) ----------------
__global__ __launch_bounds__(128) void k_head(const float* __restrict__ gsum, const int* __restrict__ gcnt,
                                              const float* __restrict__ p1, const float* __restrict__ p2,
                                              const float* __restrict__ p3,
                                              const float* __restrict__ Wex, const float* __restrict__ bex,
                                              const float* __restrict__ Wpat, const float* __restrict__ bpat,
                                              const float* __restrict__ Wc1, const float* __restrict__ bc1,
                                              const float* __restrict__ Wc2, const float* __restrict__ bc2,
                                              const float* __restrict__ Wc3, const float* __restrict__ bc3,
                                              float* __restrict__ out) {
    int g = blockIdx.x;
    int tid = threadIdx.x;
    __shared__ float pbuf[192];   // p1|p2|p3 row for this graph
    __shared__ float ex[96], xc[128], t1[64], t2[32];

    if (tid < 64)       pbuf[tid] = p1[g * 64 + tid];
    else if (tid < 128) pbuf[tid] = p2[g * 64 + tid - 64];
    if (tid < 64)       pbuf[128 + tid] = p3[g * 64 + tid];
    if (tid >= 64 && tid < 128)
        xc[tid - 64] = gsum[g * 64 + tid - 64] / fmaxf((float)gcnt[g], 1.f);
    __syncthreads();
    if (tid < 96) {
        int jj = tid & 31;
        const float* pp = &pbuf[(tid >> 5) * 64];
        float acc = bex[jj];
        for (int k = 0; k < 64; k++) acc += pp[k] * Wex[k * 32 + jj];
        ex[tid] = acc;
    }
    __syncthreads();
    if (tid < 64) {
        float acc = bpat[tid];
        for (int k = 0; k < 96; k++) acc += ex[k] * Wpat[k * 64 + tid];
        xc[64 + tid] = acc > 0.f ? acc : 0.01f * acc;
    }
    __syncthreads();
    if (tid < 64) {
        float acc = bc1[tid];
        for (int k = 0; k < 128; k++) acc += xc[k] * Wc1[k * 64 + tid];
        t1[tid] = acc > 0.f ? acc : 0.01f * acc;
    }
    __syncthreads();
    if (tid < 32) {
        float acc = bc2[tid];
        for (int k = 0; k < 64; k++) acc += t1[k] * Wc2[k * 32 + tid];
        t2[tid] = acc > 0.f ? acc : 0.01f * acc;
    }
    __syncthreads();
    if (tid < 2) {
        float acc = bc3[tid];
        for (int k = 0; k < 32; k++) acc += t2[k] * Wc3[k * 2 + tid];
        out[g * 2 + tid] = acc;
    }
}

extern "C" void kernel_launch(void* const* d_in, const int* in_sizes, int n_in,
                              void* d_out, int out_size, void* d_ws, size_t ws_size,
                              hipStream_t stream) {
    const float* X0  = (const float*)d_in[0];
    const int*   src = (const int*)d_in[1];
    const int*   dst = (const int*)d_in[2];
    const int*   gid = (const int*)d_in[3];
    const float* p1  = (const float*)d_in[4];
    const float* p2  = (const float*)d_in[5];
    const float* p3  = (const float*)d_in[6];
    const float* W1s = (const float*)d_in[7],  *W1d = (const float*)d_in[8];
    const float* a1  = (const float*)d_in[9],  *b1  = (const float*)d_in[10];
    const float* W2s = (const float*)d_in[11], *W2d = (const float*)d_in[12];
    const float* a2  = (const float*)d_in[13], *b2  = (const float*)d_in[14];
    const float* W3s = (const float*)d_in[15], *W3d = (const float*)d_in[16];
    const float* a3  = (const float*)d_in[17], *b3  = (const float*)d_in[18];
    const float* Wex = (const float*)d_in[19], *bex = (const float*)d_in[20];
    const float* Wpat= (const float*)d_in[21], *bpat= (const float*)d_in[22];
    const float* Wc1 = (const float*)d_in[23], *bc1 = (const float*)d_in[24];
    const float* Wc2 = (const float*)d_in[25], *bc2 = (const float*)d_in[26];
    const float* Wc3 = (const float*)d_in[27], *bc3 = (const float*)d_in[28];
    float* out = (float*)d_out;

    char* ws = (char*)d_ws;
    size_t off = 0;
    auto alloc = [&](size_t bytes) -> char* {
        char* p = ws + off;
        off = (off + bytes + 255) & ~(size_t)255;
        return p;
    };
    unsigned short* FS = (unsigned short*)alloc((size_t)NN * HD * 2);  // bf16
    unsigned short* FD = (unsigned short*)alloc((size_t)NN * HD * 2);  // bf16
    unsigned short* P1s = (unsigned short*)alloc((size_t)192 * 192 * 2);
    unsigned short* P1d = (unsigned short*)alloc((size_t)192 * 192 * 2);
    unsigned short* P2s = (unsigned short*)alloc((size_t)192 * 192 * 2);
    unsigned short* P2d = (unsigned short*)alloc((size_t)192 * 192 * 2);
    unsigned short* P3s = (unsigned short*)alloc((size_t)192 * 192 * 2);
    unsigned short* P3d = (unsigned short*)alloc((size_t)192 * 192 * 2);
    int* row_ptr = (int*)alloc((size_t)(NN + 1) * 4);
    int* csr_src = (int*)alloc((size_t)EE * 4);
    int* csr_dst = (int*)alloc((size_t)EE * 4);
    int* bsums   = (int*)alloc(64 * 4);
    // zeroed region (ONE memset): 3x(ACC|DEN) | counts | cursor | gsum | gcnt
    char* zbase = ws + off;
    float* ACCa = (float*)alloc((size_t)NN * HD * 4);
    float* DENa = (float*)alloc((size_t)NN * 4 * 4);
    float* ACCb = (float*)alloc((size_t)NN * HD * 4);
    float* DENb = (float*)alloc((size_t)NN * 4 * 4);
    float* ACCc = (float*)alloc((size_t)NN * HD * 4);
    float* DENc = (float*)alloc((size_t)NN * 4 * 4);
    int*   counts = (int*)alloc((size_t)NN * 4);
    int*   cursor = (int*)alloc((size_t)NN * 4);
    float* gsum   = (float*)alloc((size_t)GG * 64 * 4);
    int*   gcnt   = (int*)alloc((size_t)GG * 4);
    size_t zbytes = (size_t)((ws + off) - zbase);

    hipMemsetAsync(zbase, 0, zbytes, stream);

    int ebl = (EE + 255) / 256;
    int nb  = (NN + 1023) / 1024;
    k_count<<<ebl, 256, 0, stream>>>(dst, counts);
    k_scan_block<<<nb, 1024, 0, stream>>>(counts, row_ptr, bsums);
    k_scan_add<<<nb, 1024, 0, stream>>>(row_ptr, bsums, nb);
    k_scatter<<<ebl, 256, 0, stream>>>(src, dst, row_ptr, cursor, csr_src, csr_dst);
    {
        int total = 2 * IDS128 + 4 * IDS192;
        k_pack_all<<<(total + 255) / 256, 256, 0, stream>>>(W1s, W1d, W2s, W2d, W3s, W3d,
                                                            P1s, P1d, P2s, P2d, P3s, P3d);
    }

    int gblk = NN / 16;                 // 3125, exact
    int eblk = EE / (4 * ECH);          // 12500, exact

    // layer 1 (K = 128)
    k_gemm_mfma<128, false><<<gblk, 256, 0, stream>>>(X0, nullptr, nullptr, P1s, P1d, FS, FD);
    k_edge_atomic<<<eblk, 256, 0, stream>>>(csr_src, csr_dst, FS, FD, a1, ACCa, DENa);
    // layer 2 (K = 192): gemm input = ACCa/DENa + b1 (fused finalize)
    k_gemm_mfma<192, true><<<gblk, 256, 0, stream>>>(ACCa, DENa, b1, P2s, P2d, FS, FD);
    k_edge_atomic<<<eblk, 256, 0, stream>>>(csr_src, csr_dst, FS, FD, a2, ACCb, DENb);
    // layer 3 (K = 192): gemm input = ACCb/DENb + b2
    k_gemm_mfma<192, true><<<gblk, 256, 0, stream>>>(ACCb, DENb, b2, P3s, P3d, FS, FD);
    k_edge_atomic<<<eblk, 256, 0, stream>>>(csr_src, csr_dst, FS, FD, a3, ACCc, DENc);

    // per-graph mean (256 blocks) then head (64 blocks)
    k_graph_mean<<<GG * 4, 256, 0, stream>>>(ACCc, DENc, b3, gid, gsum, gcnt);
    k_head<<<GG, 128, 0, stream>>>(gsum, gcnt, p1, p2, p3, Wex, bex, Wpat, bpat,
                                   Wc1, bc1, Wc2, bc2, Wc3, bc3, out);
}

// Round 18
// 536.867 us; speedup vs baseline: 1.0110x; 1.0110x over previous
//
#include <hip/hip_runtime.h>
#include <cstdint>
#include <cstddef>

// Problem constants (fixed by the reference)
#define NN 50000
#define EE 400000
#define FIN 128
#define HH 3
#define DD 64
#define GG 64
#define PP 64
#define HD 192   // H*D

typedef short bf16x8 __attribute__((ext_vector_type(8)));   // 8 bf16 (4 VGPRs)
typedef float f32x4 __attribute__((ext_vector_type(4)));

__device__ inline float wsum(float v) {
#pragma unroll
    for (int m = 32; m > 0; m >>= 1) v += __shfl_xor(v, m, 64);
    return v;
}
__device__ inline int wsumi(int v) {
#pragma unroll
    for (int m = 32; m > 0; m >>= 1) v += __shfl_xor(v, m, 64);
    return v;
}

// bf16 <-> f32 (RNE)
__device__ inline float bf2f(unsigned short u) {
    union { unsigned int i; float f; } x; x.i = ((unsigned int)u) << 16; return x.f;
}
__device__ inline unsigned short f2bf(float f) {
    union { float f; unsigned int i; } x; x.f = f;
    unsigned int r = x.i + 0x7FFFu + ((x.i >> 16) & 1u);
    return (unsigned short)(r >> 16);
}

// ---------------- CSR build (dst-sorted edge order) ----------------
__global__ void k_count(const int* __restrict__ dst, int* __restrict__ counts) {
    int e = blockIdx.x * 256 + threadIdx.x;
    if (e < EE) atomicAdd(&counts[dst[e]], 1);
}

__global__ void k_scan_block(const int* __restrict__ in, int* __restrict__ out,
                             int* __restrict__ bsums) {
    __shared__ int tmp[1024];
    int tid = threadIdx.x;
    int i = blockIdx.x * 1024 + tid;
    int v = (i < NN) ? in[i] : 0;
    tmp[tid] = v;
    __syncthreads();
    for (int off = 1; off < 1024; off <<= 1) {
        int t = (tid >= off) ? tmp[tid - off] : 0;
        __syncthreads();
        tmp[tid] += t;
        __syncthreads();
    }
    if (i < NN) out[i] = tmp[tid] - v;
    if (tid == 1023) bsums[blockIdx.x] = tmp[1023];
}

// fused: each block computes its own bsums-prefix (nb <= 64) then adds it
__global__ void k_scan_add(int* __restrict__ row_ptr, const int* __restrict__ bsums, int nb) {
    __shared__ int sbase;
    int tid = threadIdx.x;
    if (tid < 64) {
        int v = (tid < blockIdx.x) ? bsums[tid] : 0;   // blockIdx.x <= nb <= 64
        v = wsumi(v);
        if (tid == 0) sbase = v;
    }
    __syncthreads();
    int i = blockIdx.x * 1024 + tid;
    if (i < NN) row_ptr[i] += sbase;
}

__global__ void k_scatter(const int* __restrict__ src, const int* __restrict__ dst,
                          const int* __restrict__ row_ptr, int* __restrict__ cursor,
                          int* __restrict__ csr_src, int* __restrict__ csr_dst) {
    int e = blockIdx.x * 256 + threadIdx.x;
    if (e >= EE) return;
    int v = dst[e];
    int pos = row_ptr[v] + atomicAdd(&cursor[v], 1);
    csr_src[pos] = src[e];
    csr_dst[pos] = v;
}

// ---------------- weight pre-pack: ALL 6 matrices, one dispatch ----------------
__device__ inline void pack_one(const float* __restrict__ W, unsigned short* __restrict__ WP,
                                int id, int Kc) {
    int lane = id & 63;
    int kc = (id >> 6) % Kc;
    int ct = (id >> 6) / Kc;
    int n = ct * 16 + (lane & 15);
    int kb = kc * 32 + (lane >> 4) * 8;
#pragma unroll
    for (int j = 0; j < 8; j++)
        WP[(unsigned)id * 8 + j] = f2bf(W[(unsigned)(kb + j) * HD + n]);
}

#define IDS128 (12 * 4 * 64)   // 3072
#define IDS192 (12 * 6 * 64)   // 4608
__global__ void k_pack_all(const float* W1s, const float* W1d,
                           const float* W2s, const float* W2d,
                           const float* W3s, const float* W3d,
                           unsigned short* P1s, unsigned short* P1d,
                           unsigned short* P2s, unsigned short* P2d,
                           unsigned short* P3s, unsigned short* P3d) {
    int idx = blockIdx.x * 256 + threadIdx.x;
    if (idx < IDS128) { pack_one(W1s, P1s, idx, 4); return; }
    idx -= IDS128;
    if (idx < IDS128) { pack_one(W1d, P1d, idx, 4); return; }
    idx -= IDS128;
    if (idx < IDS192) { pack_one(W2s, P2s, idx, 6); return; }
    idx -= IDS192;
    if (idx < IDS192) { pack_one(W2d, P2d, idx, 6); return; }
    idx -= IDS192;
    if (idx < IDS192) { pack_one(W3s, P3s, idx, 6); return; }
    idx -= IDS192;
    if (idx < IDS192) { pack_one(W3d, P3d, idx, 6); return; }
}

// ---------------- MFMA GEMM: [N,K]@[K,192] x2 (Ws,Wd); outputs bf16 ------------
// (R16 version: M-tile = 16, LDS epilogue, unsigned 32-bit indexing)
template <int K, bool FUSE>
__global__ __launch_bounds__(256) void k_gemm_mfma(const float* __restrict__ X,
                                                   const float* __restrict__ DENp,
                                                   const float* __restrict__ bprev,
                                                   const unsigned short* __restrict__ WPs,
                                                   const unsigned short* __restrict__ WPd,
                                                   unsigned short* __restrict__ FS,
                                                   unsigned short* __restrict__ FD) {
    constexpr int Kc = K / 32;
    __shared__ unsigned short xs[16][K + 8];
    __shared__ unsigned short cs[16][392];   // [row][0..191]=FS cols, [192..383]=FD cols
    int tid = threadIdx.x;
    int row0 = blockIdx.x * 16;
    for (int idx = tid; idx < 16 * K; idx += 256) {
        int r = idx / K, k = idx - r * K;
        int row = row0 + r;
        float val;
        if (FUSE) {
            float den = DENp[(unsigned)(row * 4 + (k >> 6))];
            val = X[(unsigned)(row * K + k)] / fmaxf(den, 1e-9f) + bprev[k];
        } else {
            val = X[(unsigned)(row * K + k)];
        }
        xs[r][k] = f2bf(val);
    }
    __syncthreads();

    int lane = tid & 63, wv = tid >> 6;
    int m = lane & 15, quad = lane >> 4;
    f32x4 acc[6];
#pragma unroll
    for (int t = 0; t < 6; t++) acc[t] = (f32x4){0.f, 0.f, 0.f, 0.f};

    for (int kc = 0; kc < Kc; kc++) {
        bf16x8 a = *(const bf16x8*)&xs[m][kc * 32 + quad * 8];
#pragma unroll
        for (int t = 0; t < 6; t++) {
            int ct = wv * 6 + t;                       // 0..23
            const unsigned short* wp = (ct < 12) ? WPs : WPd;
            int c = (ct < 12) ? ct : ct - 12;
            bf16x8 b = *(const bf16x8*)&wp[(unsigned)(((c * Kc + kc) * 64 + lane) * 8)];
            acc[t] = __builtin_amdgcn_mfma_f32_16x16x32_bf16(a, b, acc[t], 0, 0, 0);
        }
    }
#pragma unroll
    for (int t = 0; t < 6; t++) {
        int ct = wv * 6 + t;
#pragma unroll
        for (int r = 0; r < 4; r++)
            cs[quad * 4 + r][ct * 16 + m] = f2bf(acc[t][r]);
    }
    __syncthreads();
#pragma unroll
    for (int it = 0; it < 3; it++) {
        int c = tid + it * 256;
        int hm = c / 384;                              // 0=FS, 1=FD
        int cc = c - hm * 384;
        int row = cc / 24, ch = cc - row * 24;
        unsigned short* OUT = hm ? FD : FS;
        *(bf16x8*)&OUT[(unsigned)((row0 + row) * HD + ch * 8)] =
            *(const bf16x8*)&cs[row][hm * 192 + ch * 8];
    }
}

// ---------------- edge-parallel GATv2 on dst-sorted edges + run merge ----------
// R15 structure, plus two wave-uniformity exploits:
//  (1) u/v broadcast to SGPRs via readfirstlane -> scalar branches + SADDR loads
//  (2) FD row hoisted across the dst-run (mean degree 8 => ~80% of FD loads
//      were redundant); g array 24 VGPRs -> 3.
// Lane=feature identity in gathers and atomic flush preserved (R14 lesson).
#define ECH 8
__global__ __launch_bounds__(256) void k_edge_atomic(const int* __restrict__ csr_src,
                                                     const int* __restrict__ csr_dst,
                                                     const unsigned short* __restrict__ FS,
                                                     const unsigned short* __restrict__ FD,
                                                     const float* __restrict__ A,
                                                     float* __restrict__ ACC,
                                                     float* __restrict__ DEN) {
    int wv = threadIdx.x >> 6, lane = threadIdx.x & 63;
    int e0 = blockIdx.x * (4 * ECH) + wv * ECH;
    float a0 = A[lane], a1 = A[64 + lane], a2 = A[128 + lane];

    int u[ECH], v[ECH];
#pragma unroll
    for (int i = 0; i < ECH; i++) {
        u[i] = __builtin_amdgcn_readfirstlane(csr_src[e0 + i]);   // wave-uniform -> SGPR
        v[i] = __builtin_amdgcn_readfirstlane(csr_dst[e0 + i]);
    }
    float f[ECH][3];
#pragma unroll
    for (int i = 0; i < ECH; i++) {
        size_t bu = (size_t)u[i] * HD;
        f[i][0] = bf2f(FS[bu + lane]);
        f[i][1] = bf2f(FS[bu + 64 + lane]);
        f[i][2] = bf2f(FS[bu + 128 + lane]);
    }
    // FD row hoisted per dst-run (scalar branch; v uniform)
    float w[ECH][3];
    float g0 = 0.f, g1 = 0.f, g2 = 0.f;
#pragma unroll
    for (int i = 0; i < ECH; i++) {
        if (i == 0 || v[i] != v[i - 1]) {
            size_t bv = (size_t)v[i] * HD;
            g0 = bf2f(FD[bv + lane]);
            g1 = bf2f(FD[bv + 64 + lane]);
            g2 = bf2f(FD[bv + 128 + lane]);
        }
        float s0 = f[i][0] + g0; s0 = s0 > 0.f ? s0 : 0.2f * s0;
        float s1 = f[i][1] + g1; s1 = s1 > 0.f ? s1 : 0.2f * s1;
        float s2 = f[i][2] + g2; s2 = s2 > 0.f ? s2 : 0.2f * s2;
        w[i][0] = s0 * a0; w[i][1] = s1 * a1; w[i][2] = s2 * a2;
    }
#pragma unroll
    for (int i = 0; i < ECH; i++)
#pragma unroll
        for (int h = 0; h < 3; h++) w[i][h] = wsum(w[i][h]);
#pragma unroll
    for (int i = 0; i < ECH; i++)
#pragma unroll
        for (int h = 0; h < 3; h++) w[i][h] = __expf(w[i][h]);

    // run-merge: consecutive sorted edges sharing dst -> single atomic flush
    float r0 = 0.f, r1 = 0.f, r2 = 0.f, d0 = 0.f, d1 = 0.f, d2 = 0.f;
    int vcur = v[0];
#pragma unroll
    for (int i = 0; i < ECH; i++) {
        if (v[i] != vcur) {
            size_t bv = (size_t)vcur * HD;
            atomicAdd(&ACC[bv + lane], r0);
            atomicAdd(&ACC[bv + 64 + lane], r1);
            atomicAdd(&ACC[bv + 128 + lane], r2);
            if (lane < 3) {
                float dv = lane == 0 ? d0 : (lane == 1 ? d1 : d2);
                atomicAdd(&DEN[vcur * 4 + lane], dv);
            }
            vcur = v[i];
            r0 = r1 = r2 = 0.f; d0 = d1 = d2 = 0.f;
        }
        r0 += w[i][0] * f[i][0]; d0 += w[i][0];
        r1 += w[i][1] * f[i][1]; d1 += w[i][1];
        r2 += w[i][2] * f[i][2]; d2 += w[i][2];
    }
    {
        size_t bv = (size_t)vcur * HD;
        atomicAdd(&ACC[bv + lane], r0);
        atomicAdd(&ACC[bv + 64 + lane], r1);
        atomicAdd(&ACC[bv + 128 + lane], r2);
        if (lane < 3) {
            float dv = lane == 0 ? d0 : (lane == 1 ? d1 : d2);
            atomicAdd(&DEN[vcur * 4 + lane], dv);
        }
    }
}

// ---------------- final: per-graph mean (256 blocks = 4 per graph) -------------
__global__ __launch_bounds__(256) void k_graph_mean(const float* __restrict__ ACC,
                                                    const float* __restrict__ DEN,
                                                    const float* __restrict__ bias,
                                                    const int* __restrict__ gids,
                                                    float* __restrict__ gsum,
                                                    int* __restrict__ gcnt) {
    int g = blockIdx.x >> 2, q = blockIdx.x & 3;
    int lo, hi;
    {
        int a = 0, b = NN;
        while (a < b) { int m = (a + b) >> 1; if (gids[m] < g) a = m + 1; else b = m; }
        lo = a;
        b = NN;
        while (a < b) { int m = (a + b) >> 1; if (gids[m] < g + 1) a = m + 1; else b = m; }
        hi = a;
    }
    int len = hi - lo;
    int qlen = (len + 3) >> 2;
    int s = lo + q * qlen;
    int e = s + qlen; if (e > hi) e = hi;
    int lane = threadIdx.x & 63, wv = threadIdx.x >> 6;

    float acc = 0.f;
    for (int v = s + wv; v < e; v += 4) {
        float r = 0.f;
#pragma unroll
        for (int h = 0; h < 3; h++) {
            float den = DEN[(unsigned)(v * 4 + h)];
            r += ACC[(unsigned)(v * HD + h * 64 + lane)] / fmaxf(den, 1e-9f) + bias[h * 64 + lane];
        }
        acc += r * (1.f / 3.f);
    }
    __shared__ float red[4][64];
    red[wv][lane] = acc;
    __syncthreads();
    if (wv == 0) {
        float t = red[0][lane] + red[1][lane] + red[2][lane] + red[3][lane];
        if (e > s) {
            atomicAdd(&gsum[g * 64 + lane], t);
            if (lane == 0) atomicAdd(&gcnt[g], e - s);
        }
    }
}

// ---------------- head: one block PER GRAPH (64 blocks) ----------------
__global__ __launch_bounds__(128) void k_head(const float* __restrict__ gsum, const int* __restrict__ gcnt,
                                              const float* __restrict__ p1, const float* __restrict__ p2,
                                              const float* __restrict__ p3,
                                              const float* __restrict__ Wex, const float* __restrict__ bex,
                                              const float* __restrict__ Wpat, const float* __restrict__ bpat,
                                              const float* __restrict__ Wc1, const float* __restrict__ bc1,
                                              const float* __restrict__ Wc2, const float* __restrict__ bc2,
                                              const float* __restrict__ Wc3, const float* __restrict__ bc3,
                                              float* __restrict__ out) {
    int g = blockIdx.x;
    int tid = threadIdx.x;
    __shared__ float pbuf[192];   // p1|p2|p3 row for this graph
    __shared__ float ex[96], xc[128], t1[64], t2[32];

    if (tid < 64)       pbuf[tid] = p1[g * 64 + tid];
    else if (tid < 128) pbuf[tid] = p2[g * 64 + tid - 64];
    if (tid < 64)       pbuf[128 + tid] = p3[g * 64 + tid];
    if (tid >= 64 && tid < 128)
        xc[tid - 64] = gsum[g * 64 + tid - 64] / fmaxf((float)gcnt[g], 1.f);
    __syncthreads();
    if (tid < 96) {
        int jj = tid & 31;
        const float* pp = &pbuf[(tid >> 5) * 64];
        float acc = bex[jj];
        for (int k = 0; k < 64; k++) acc += pp[k] * Wex[k * 32 + jj];
        ex[tid] = acc;
    }
    __syncthreads();
    if (tid < 64) {
        float acc = bpat[tid];
        for (int k = 0; k < 96; k++) acc += ex[k] * Wpat[k * 64 + tid];
        xc[64 + tid] = acc > 0.f ? acc : 0.01f * acc;
    }
    __syncthreads();
    if (tid < 64) {
        float acc = bc1[tid];
        for (int k = 0; k < 128; k++) acc += xc[k] * Wc1[k * 64 + tid];
        t1[tid] = acc > 0.f ? acc : 0.01f * acc;
    }
    __syncthreads();
    if (tid < 32) {
        float acc = bc2[tid];
        for (int k = 0; k < 64; k++) acc += t1[k] * Wc2[k * 32 + tid];
        t2[tid] = acc > 0.f ? acc : 0.01f * acc;
    }
    __syncthreads();
    if (tid < 2) {
        float acc = bc3[tid];
        for (int k = 0; k < 32; k++) acc += t2[k] * Wc3[k * 2 + tid];
        out[g * 2 + tid] = acc;
    }
}

extern "C" void kernel_launch(void* const* d_in, const int* in_sizes, int n_in,
                              void* d_out, int out_size, void* d_ws, size_t ws_size,
                              hipStream_t stream) {
    const float* X0  = (const float*)d_in[0];
    const int*   src = (const int*)d_in[1];
    const int*   dst = (const int*)d_in[2];
    const int*   gid = (const int*)d_in[3];
    const float* p1  = (const float*)d_in[4];
    const float* p2  = (const float*)d_in[5];
    const float* p3  = (const float*)d_in[6];
    const float* W1s = (const float*)d_in[7],  *W1d = (const float*)d_in[8];
    const float* a1  = (const float*)d_in[9],  *b1  = (const float*)d_in[10];
    const float* W2s = (const float*)d_in[11], *W2d = (const float*)d_in[12];
    const float* a2  = (const float*)d_in[13], *b2  = (const float*)d_in[14];
    const float* W3s = (const float*)d_in[15], *W3d = (const float*)d_in[16];
    const float* a3  = (const float*)d_in[17], *b3  = (const float*)d_in[18];
    const float* Wex = (const float*)d_in[19], *bex = (const float*)d_in[20];
    const float* Wpat= (const float*)d_in[21], *bpat= (const float*)d_in[22];
    const float* Wc1 = (const float*)d_in[23], *bc1 = (const float*)d_in[24];
    const float* Wc2 = (const float*)d_in[25], *bc2 = (const float*)d_in[26];
    const float* Wc3 = (const float*)d_in[27], *bc3 = (const float*)d_in[28];
    float* out = (float*)d_out;

    char* ws = (char*)d_ws;
    size_t off = 0;
    auto alloc = [&](size_t bytes) -> char* {
        char* p = ws + off;
        off = (off + bytes + 255) & ~(size_t)255;
        return p;
    };
    unsigned short* FS = (unsigned short*)alloc((size_t)NN * HD * 2);  // bf16
    unsigned short* FD = (unsigned short*)alloc((size_t)NN * HD * 2);  // bf16
    unsigned short* P1s = (unsigned short*)alloc((size_t)192 * 192 * 2);
    unsigned short* P1d = (unsigned short*)alloc((size_t)192 * 192 * 2);
    unsigned short* P2s = (unsigned short*)alloc((size_t)192 * 192 * 2);
    unsigned short* P2d = (unsigned short*)alloc((size_t)192 * 192 * 2);
    unsigned short* P3s = (unsigned short*)alloc((size_t)192 * 192 * 2);
    unsigned short* P3d = (unsigned short*)alloc((size_t)192 * 192 * 2);
    int* row_ptr = (int*)alloc((size_t)(NN + 1) * 4);
    int* csr_src = (int*)alloc((size_t)EE * 4);
    int* csr_dst = (int*)alloc((size_t)EE * 4);
    int* bsums   = (int*)alloc(64 * 4);
    // zeroed region (ONE memset): 3x(ACC|DEN) | counts | cursor | gsum | gcnt
    char* zbase = ws + off;
    float* ACCa = (float*)alloc((size_t)NN * HD * 4);
    float* DENa = (float*)alloc((size_t)NN * 4 * 4);
    float* ACCb = (float*)alloc((size_t)NN * HD * 4);
    float* DENb = (float*)alloc((size_t)NN * 4 * 4);
    float* ACCc = (float*)alloc((size_t)NN * HD * 4);
    float* DENc = (float*)alloc((size_t)NN * 4 * 4);
    int*   counts = (int*)alloc((size_t)NN * 4);
    int*   cursor = (int*)alloc((size_t)NN * 4);
    float* gsum   = (float*)alloc((size_t)GG * 64 * 4);
    int*   gcnt   = (int*)alloc((size_t)GG * 4);
    size_t zbytes = (size_t)((ws + off) - zbase);

    hipMemsetAsync(zbase, 0, zbytes, stream);

    int ebl = (EE + 255) / 256;
    int nb  = (NN + 1023) / 1024;
    k_count<<<ebl, 256, 0, stream>>>(dst, counts);
    k_scan_block<<<nb, 1024, 0, stream>>>(counts, row_ptr, bsums);
    k_scan_add<<<nb, 1024, 0, stream>>>(row_ptr, bsums, nb);
    k_scatter<<<ebl, 256, 0, stream>>>(src, dst, row_ptr, cursor, csr_src, csr_dst);
    {
        int total = 2 * IDS128 + 4 * IDS192;
        k_pack_all<<<(total + 255) / 256, 256, 0, stream>>>(W1s, W1d, W2s, W2d, W3s, W3d,
                                                            P1s, P1d, P2s, P2d, P3s, P3d);
    }

    int gblk = NN / 16;                 // 3125, exact
    int eblk = EE / (4 * ECH);          // 12500, exact

    // layer 1 (K = 128)
    k_gemm_mfma<128, false><<<gblk, 256, 0, stream>>>(X0, nullptr, nullptr, P1s, P1d, FS, FD);
    k_edge_atomic<<<eblk, 256, 0, stream>>>(csr_src, csr_dst, FS, FD, a1, ACCa, DENa);
    // layer 2 (K = 192): gemm input = ACCa/DENa + b1 (fused finalize)
    k_gemm_mfma<192, true><<<gblk, 256, 0, stream>>>(ACCa, DENa, b1, P2s, P2d, FS, FD);
    k_edge_atomic<<<eblk, 256, 0, stream>>>(csr_src, csr_dst, FS, FD, a2, ACCb, DENb);
    // layer 3 (K = 192): gemm input = ACCb/DENb + b2
    k_gemm_mfma<192, true><<<gblk, 256, 0, stream>>>(ACCb, DENb, b2, P3s, P3d, FS, FD);
    k_edge_atomic<<<eblk, 256, 0, stream>>>(csr_src, csr_dst, FS, FD, a3, ACCc, DENc);

    // per-graph mean (256 blocks) then head (64 blocks)
    k_graph_mean<<<GG * 4, 256, 0, stream>>>(ACCc, DENc, b3, gid, gsum, gcnt);
    k_head<<<GG, 128, 0, stream>>>(gsum, gcnt, p1, p2, p3, Wex, bex, Wpat, bpat,
                                   Wc1, bc1, Wc2, bc2, Wc3, bc3, out);
}